// Round 4
// baseline (1196.523 us; speedup 1.0000x reference)
//
#include <hip/hip_runtime.h>

#define Bdim   4096
#define INdim  4096
#define OUTdim 2048
#define Knz    32

typedef float  f4  __attribute__((ext_vector_type(4)));
typedef short  s4  __attribute__((ext_vector_type(4)));

// f32 -> bf16 round-to-nearest-even
__device__ inline unsigned short f2bf(float f) {
  unsigned u = __float_as_uint(f);
  u += 0x7fffu + ((u >> 16) & 1u);
  return (unsigned short)(u >> 16);
}

// Kernel 1: xT[i][b] = bf16(x[b][i]).  64x64 tiles via LDS.  ~96 MB stream at HBM BW.
// nt on both sides: pure stream, keep it out of L2.
__global__ __launch_bounds__(256) void k_transpose(const float* __restrict__ x,
                                                   unsigned short* __restrict__ xT) {
  __shared__ float tile[64][65];
  const int bi = blockIdx.x;      // 64-row tile (b dim)
  const int ii = blockIdx.y;      // 64-col tile (IN dim)
  const int t = threadIdx.x;
  const int r = t >> 4;           // 0..15
  const int c = t & 15;           // 0..15
#pragma unroll
  for (int rr = 0; rr < 64; rr += 16) {
    const f4 v = __builtin_nontemporal_load(reinterpret_cast<const f4*>(
        &x[(size_t)(bi * 64 + rr + r) * INdim + ii * 64 + c * 4]));
    tile[rr + r][c * 4 + 0] = v.x;
    tile[rr + r][c * 4 + 1] = v.y;
    tile[rr + r][c * 4 + 2] = v.z;
    tile[rr + r][c * 4 + 3] = v.w;
  }
  __syncthreads();
#pragma unroll
  for (int rr = 0; rr < 64; rr += 16) {
    const int il = rr + r;
    s4 o;
    o.x = (short)f2bf(tile[c * 4 + 0][il]);
    o.y = (short)f2bf(tile[c * 4 + 1][il]);
    o.z = (short)f2bf(tile[c * 4 + 2][il]);
    o.w = (short)f2bf(tile[c * 4 + 3][il]);
    __builtin_nontemporal_store(o, reinterpret_cast<s4*>(
        &xT[(size_t)(ii * 64 + il) * Bdim + bi * 64 + c * 4]));
  }
}

// Kernel 2: gather-dot.
// 2048 blocks. wg -> {xcd = wg&7, op' = wg>>3}; XCD x owns b-range
// [x*512, x*512+512) (4MB xT slice in its L2), phase-ordered as two 2MB
// subtiles: bt = x*2 + (op'>>7), o-panel op = op'&127.
// Block = 256 b x 16 o. Wave w -> 4 o; lane -> 4 consecutive b (uint2 gather,
// 512B/wave-instr, wave-uniform col/val -> s_load).
// acc[4][4] = 16 VGPRs; launch_bounds(256,8) targets VGPR<=64 -> 8 waves/SIMD.
// Plain stores (NOT nt): 64B line filled by 4 waves of one block -> L2 merges.
__global__ __launch_bounds__(256, 8) void k_gather(const unsigned short* __restrict__ xT,
                                                   const int* __restrict__ cols,
                                                   const float* __restrict__ values,
                                                   float* __restrict__ out) {
  const int wg = blockIdx.x;                 // 0..2047
  const int xcd = wg & 7;
  const int opp = wg >> 3;                   // 0..255 per XCD
  const int bt = xcd * 2 + (opp >> 7);       // 16 b-tiles of 256
  const int op = opp & 127;                  // 128 o-panels of 16
  const int w = threadIdx.x >> 6;            // wave 0..3 -> o sub-panel
  const int l = threadIdx.x & 63;            // lane -> 4 consecutive b
  const int b0 = bt * 256 + l * 4;
  const int o0 = op * 16 + w * 4;

  float acc[4][4];                           // [oc][b-sub], static idx -> registers
#pragma unroll
  for (int i = 0; i < 4; ++i)
#pragma unroll
    for (int j = 0; j < 4; ++j) acc[i][j] = 0.f;

  const unsigned short* __restrict__ xb = xT + b0;

#pragma unroll
  for (int oc = 0; oc < 4; ++oc) {
    const int o = o0 + oc;
    const int* __restrict__ cp = cols + o * Knz;
    const float* __restrict__ vp = values + o * Knz;
#pragma unroll
    for (int k = 0; k < Knz; ++k) {
      const int col = cp[k];                 // wave-uniform -> s_load
      const float val = vp[k];               // wave-uniform -> s_load
      const uint2 u = *reinterpret_cast<const uint2*>(&xb[(size_t)col * Bdim]);
      acc[oc][0] = fmaf(__uint_as_float(u.x << 16),          val, acc[oc][0]);
      acc[oc][1] = fmaf(__uint_as_float(u.x & 0xffff0000u),  val, acc[oc][1]);
      acc[oc][2] = fmaf(__uint_as_float(u.y << 16),          val, acc[oc][2]);
      acc[oc][3] = fmaf(__uint_as_float(u.y & 0xffff0000u),  val, acc[oc][3]);
    }
  }

  // 4 rows x 16B stores; line completed by this block's 4 waves.
#pragma unroll
  for (int r = 0; r < 4; ++r) {
    *reinterpret_cast<f4*>(&out[(size_t)(b0 + r) * OUTdim + o0]) =
        (f4){acc[0][r], acc[1][r], acc[2][r], acc[3][r]};
  }
}

// Correct-but-slow fallback if ws can't hold xT (32 MB).
__global__ __launch_bounds__(256) void k_naive(const float* __restrict__ x,
                                               const float* __restrict__ values,
                                               const int* __restrict__ cols,
                                               float* __restrict__ out) {
  const size_t id = (size_t)blockIdx.x * 256 + threadIdx.x;
  const int o = (int)(id % OUTdim);
  const int b = (int)(id / OUTdim);
  float a = 0.f;
  for (int k = 0; k < Knz; ++k) {
    const int col = cols[o * Knz + k];
    a = fmaf(x[(size_t)b * INdim + col], values[o * Knz + k], a);
  }
  out[id] = a;
}

extern "C" void kernel_launch(void* const* d_in, const int* in_sizes, int n_in,
                              void* d_out, int out_size, void* d_ws, size_t ws_size,
                              hipStream_t stream) {
  const float* x = (const float*)d_in[0];
  const float* values = (const float*)d_in[1];
  const int* cols = (const int*)d_in[2];
  float* out = (float*)d_out;

  const size_t need = (size_t)INdim * Bdim * sizeof(unsigned short);  // 32 MB
  if (ws_size >= need) {
    unsigned short* xT = (unsigned short*)d_ws;
    k_transpose<<<dim3(64, 64), 256, 0, stream>>>(x, xT);
    k_gather<<<2048, 256, 0, stream>>>(xT, cols, values, out);
  } else {
    k_naive<<<(Bdim * (size_t)OUTdim) / 256, 256, 0, stream>>>(x, values, cols, out);
  }
}

// Round 5
// 139.137 us; speedup vs baseline: 8.5996x; 8.5996x over previous
//
#include <hip/hip_runtime.h>

#define Bdim   4096
#define INdim  4096
#define OUTdim 2048
#define Knz    32

typedef float  f4  __attribute__((ext_vector_type(4)));
typedef short  s4  __attribute__((ext_vector_type(4)));

// f32 -> bf16 round-to-nearest-even
__device__ inline unsigned short f2bf(float f) {
  unsigned u = __float_as_uint(f);
  u += 0x7fffu + ((u >> 16) & 1u);
  return (unsigned short)(u >> 16);
}

// Kernel 1: xT[i][b] = bf16(x[b][i]).  64x64 tiles via LDS.  96 MB stream — at
// HBM floor (~15us).  nt on both sides: keep the stream out of L2.
__global__ __launch_bounds__(256) void k_transpose(const float* __restrict__ x,
                                                   unsigned short* __restrict__ xT) {
  __shared__ float tile[64][65];
  const int bi = blockIdx.x;      // 64-row tile (b dim)
  const int ii = blockIdx.y;      // 64-col tile (IN dim)
  const int t = threadIdx.x;
  const int r = t >> 4;           // 0..15
  const int c = t & 15;           // 0..15
#pragma unroll
  for (int rr = 0; rr < 64; rr += 16) {
    const f4 v = __builtin_nontemporal_load(reinterpret_cast<const f4*>(
        &x[(size_t)(bi * 64 + rr + r) * INdim + ii * 64 + c * 4]));
    tile[rr + r][c * 4 + 0] = v.x;
    tile[rr + r][c * 4 + 1] = v.y;
    tile[rr + r][c * 4 + 2] = v.z;
    tile[rr + r][c * 4 + 3] = v.w;
  }
  __syncthreads();
#pragma unroll
  for (int rr = 0; rr < 64; rr += 16) {
    const int il = rr + r;
    s4 o;
    o.x = (short)f2bf(tile[c * 4 + 0][il]);
    o.y = (short)f2bf(tile[c * 4 + 1][il]);
    o.z = (short)f2bf(tile[c * 4 + 2][il]);
    o.w = (short)f2bf(tile[c * 4 + 3][il]);
    __builtin_nontemporal_store(o, reinterpret_cast<s4*>(
        &xT[(size_t)(ii * 64 + il) * Bdim + bi * 64 + c * 4]));
  }
}

// Kernel 2: gather-dot.
// 2048 blocks. wg -> {xcd = wg&7, opp = wg>>3}. XCD x owns b-range
// [x*512, (x+1)*512), processed as two phase-ordered 2MB subtiles:
// bt = x*2 + (opp>>7); o-panel op = opp&127 (16 outputs).
// Wave w -> 4 consecutive o; lane -> 4 consecutive b (uint2 gather = 512B/wave
// from one 64B-aligned L2-resident run; col/val wave-uniform -> s_load).
// acc[4][4] = 16 VGPRs, static indexing only. NO forced launch_bounds waves:
// R4 showed (256,8) makes the allocator spill everything to scratch.
// Plain stores: each 64B out line is completed by this block's 4 waves.
__global__ __launch_bounds__(256) void k_gather(const unsigned short* __restrict__ xT,
                                                const int* __restrict__ cols,
                                                const float* __restrict__ values,
                                                float* __restrict__ out) {
  const int wg = blockIdx.x;                 // 0..2047
  const int xcd = wg & 7;
  const int opp = wg >> 3;                   // 0..255 per XCD
  const int bt = xcd * 2 + (opp >> 7);       // 16 b-tiles of 256
  const int op = opp & 127;                  // 128 o-panels of 16
  const int w = threadIdx.x >> 6;            // wave 0..3 -> o sub-panel
  const int l = threadIdx.x & 63;            // lane -> 4 consecutive b
  const int b0 = bt * 256 + l * 4;
  const int o0 = op * 16 + w * 4;

  float acc[4][4];                           // [oc][b-sub], static idx -> regs
#pragma unroll
  for (int i = 0; i < 4; ++i)
#pragma unroll
    for (int j = 0; j < 4; ++j) acc[i][j] = 0.f;

  const unsigned short* __restrict__ xb = xT + b0;

#pragma unroll
  for (int oc = 0; oc < 4; ++oc) {
    const int o = o0 + oc;
    const int* __restrict__ cp = cols + o * Knz;
    const float* __restrict__ vp = values + o * Knz;
#pragma unroll
    for (int k = 0; k < Knz; ++k) {
      const int col = cp[k];                 // wave-uniform -> s_load
      const float val = vp[k];               // wave-uniform -> s_load
      const uint2 u = *reinterpret_cast<const uint2*>(&xb[(size_t)col * Bdim]);
      acc[oc][0] = fmaf(__uint_as_float(u.x << 16),          val, acc[oc][0]);
      acc[oc][1] = fmaf(__uint_as_float(u.x & 0xffff0000u),  val, acc[oc][1]);
      acc[oc][2] = fmaf(__uint_as_float(u.y << 16),          val, acc[oc][2]);
      acc[oc][3] = fmaf(__uint_as_float(u.y & 0xffff0000u),  val, acc[oc][3]);
    }
  }

  // 4 rows x 16B cached stores; line completed by this block's 4 waves.
#pragma unroll
  for (int r = 0; r < 4; ++r) {
    *reinterpret_cast<f4*>(&out[(size_t)(b0 + r) * OUTdim + o0]) =
        (f4){acc[0][r], acc[1][r], acc[2][r], acc[3][r]};
  }
}

// Correct-but-slow fallback if ws can't hold xT (32 MB).
__global__ __launch_bounds__(256) void k_naive(const float* __restrict__ x,
                                               const float* __restrict__ values,
                                               const int* __restrict__ cols,
                                               float* __restrict__ out) {
  const size_t id = (size_t)blockIdx.x * 256 + threadIdx.x;
  const int o = (int)(id % OUTdim);
  const int b = (int)(id / OUTdim);
  float a = 0.f;
  for (int k = 0; k < Knz; ++k) {
    const int col = cols[o * Knz + k];
    a = fmaf(x[(size_t)b * INdim + col], values[o * Knz + k], a);
  }
  out[id] = a;
}

extern "C" void kernel_launch(void* const* d_in, const int* in_sizes, int n_in,
                              void* d_out, int out_size, void* d_ws, size_t ws_size,
                              hipStream_t stream) {
  const float* x = (const float*)d_in[0];
  const float* values = (const float*)d_in[1];
  const int* cols = (const int*)d_in[2];
  float* out = (float*)d_out;

  const size_t need = (size_t)INdim * Bdim * sizeof(unsigned short);  // 32 MB
  if (ws_size >= need) {
    unsigned short* xT = (unsigned short*)d_ws;
    k_transpose<<<dim3(64, 64), 256, 0, stream>>>(x, xT);
    k_gather<<<2048, 256, 0, stream>>>(xT, cols, values, out);
  } else {
    k_naive<<<(Bdim * (size_t)OUTdim) / 256, 256, 0, stream>>>(x, values, cols, out);
  }
}